// Round 11
// baseline (270.024 us; speedup 1.0000x reference)
//
#include <hip/hip_runtime.h>
#include <hip/hip_bf16.h>

typedef __hip_bfloat16 bf16;

#define R_NUM 40000
#define E_NUM 500000
#define HIST_BLOCKS 1954   // ceil(E/256)
#define XF_BLOCKS 1250     // R/32: 32-row blocks = 4 waves x 8 rows, wave-private rows
#define ZERO_BLOCKS 157    // ceil(R/256)

// ---- packed wbuf layout (f32 element offsets) ----
// PK_P1 : p1w packed [g][j][di]           (16*256)
// PK_XF : [l][g][m][j][di], m=0:pwb 1:aw 2:pwt 3:rw   (2*16*4*256)
#define PK_P1 0
#define PK_P1B 4096
#define PK_XF 4160
#define PK_AB 36928
#define PK_APB 37056
#define PK_RB 37184
#define PK_ABIN 37312
#define PK_AVEC 37472
#define PK_END 37600
#define PACK_BLOCKS 147  // ceil(PK_END/256)
#define INIT_BLOCKS (PACK_BLOCKS + ZERO_BLOCKS)

// ---------------- new-path ws layout (bytes) ----------------
#define N_CNTS 0          // 160000
#define N_ROWP 160000     // 40001 ints (incl. row_ptr[R]=E), padded
#define N_RANK 320256     // E ints
#define N_STB 2320384     // E*4 + 256 zero pad -> ends 4,320,640
#define N_FLAG 4320640    // 2 ints
#define N_WBUF 4320896    // PK_END*4 = 150400 -> ends 4,471,296
#define N_XMP0 4471296
#define N_HR0 14711296
#define N_XMP1 35191296
#define N_HR1 45431296
#define NEED2 65911296ull

// ---------------- legacy (PlanD fallback) ws layout ----------------
#define W_P1W 0
#define W_P1B 4096
#define W_APW 4160
#define W_APB 20544
#define W_ABIN 20672
#define W_AVEC 20832
#define W_AW 20960
#define W_AB 29152
#define W_RW 29280
#define W_RB 37472
#define W_END 37600
#define WCONV_BLOCKS 147

#define O_FLAG 0
#define O_WBUF 256
#define O_ROWP 150784
#define O_CNTS 310784
#define O_STB 635136
#define O_BIG 2635392

static __device__ __forceinline__ float b2f(bf16 x) { return __bfloat162float(x); }
static __device__ __forceinline__ float ldv(const float* p, size_t i) { return p[i]; }
static __device__ __forceinline__ float ldv(const bf16* p, size_t i) { return __bfloat162float(p[i]); }
static __device__ __forceinline__ void stv(float* p, size_t i, float v) { p[i] = v; }
static __device__ __forceinline__ void stv(bf16* p, size_t i, float v) { p[i] = __float2bfloat16(v); }

// round-to-nearest-even f32 -> bf16 bits
static __device__ __forceinline__ unsigned int f2bb(float x) {
  union { float f; unsigned int u; } v;
  v.f = x;
  unsigned int r = v.u + 0x7FFFu + ((v.u >> 16) & 1u);
  return r >> 16;
}
static __device__ __forceinline__ unsigned int packxm(float xt, float mt) {
  return f2bb(xt) | (f2bb(mt) << 16);
}

static __device__ __forceinline__ void load_edge(const unsigned int* __restrict__ w, int e,
                                                 int i64, int& h, int& t, int& b) {
  if (i64) {
    h = (int)w[6 * e + 0];
    t = (int)w[6 * e + 2];
    b = (int)w[6 * e + 4];
  } else {
    h = (int)w[3 * e + 0];
    t = (int)w[3 * e + 1];
    b = (int)w[3 * e + 2];
  }
}

// ---------------- k_init: detect + pack + zero counts + stb pad (1 launch) -----------------
// Pack blocks SELF-detect the dtype flags (one wave, ~50 loads, trivial) so detect+pack fuse
// without a cross-block dependency. Block 0 publishes flags for downstream kernels.

__global__ void __launch_bounds__(256) k_init(
    const unsigned int* __restrict__ trip_w, const unsigned short* __restrict__ emb16,
    int* __restrict__ flag, int* __restrict__ counts, int* __restrict__ stb, const void* p1w,
    const void* p1b, const void* apw, const void* apb, const void* abin, const void* avec,
    const void* aw, const void* ab, const void* rw, const void* rb, float* __restrict__ wbuf) {
  int tid = threadIdx.x;
  int bid = blockIdx.x;
  if (bid < PACK_BLOCKS) {
    __shared__ int sfl;
    if (tid < 64) {
      unsigned int acc = 0;
      for (int i = tid; i < 1024; i += 64) acc |= trip_w[2 * i + 1];
      int votes = 0;
      for (int i = tid; i < 2048; i += 64) {
        unsigned short u = emb16[2 * i];
        int ex = (u >> 7) & 0xFF;
        if (ex >= 90 && ex <= 130) votes++;
      }
      for (int off = 1; off < 64; off <<= 1) {
        acc |= __shfl_xor(acc, off);
        votes += __shfl_xor(votes, off);
      }
      if (tid == 0) {
        sfl = (votes < 1024) ? 1 : 0;
        if (bid == 0) {
          flag[0] = (acc == 0) ? 1 : 0;
          flag[1] = sfl;
        }
      }
    }
    __syncthreads();
    int f32w = sfl;
    int i = bid * 256 + tid;
    if (i >= PK_END) return;
    const void* src;
    int off;
    if (i < PK_P1B) {
      int g = i >> 8, r = i & 255, j = r >> 2, di = r & 3;
      src = p1w;
      off = (g * 4 + di) * 64 + j;
    } else if (i < PK_XF) {
      src = p1b;
      off = i - PK_P1B;
    } else if (i < PK_AB) {
      int t = i - PK_XF;
      int l = t >> 14;
      t &= 16383;
      int g = t >> 10;
      t &= 1023;
      int m = t >> 8;
      int r = t & 255, j = r >> 2, di = r & 3;
      int ii = g * 4 + di;
      if (m == 0) { src = apw; off = l * 8192 + 4096 + ii * 64 + j; }
      else if (m == 1) { src = aw; off = l * 4096 + ii * 64 + j; }
      else if (m == 2) { src = apw; off = l * 8192 + ii * 64 + j; }
      else { src = rw; off = l * 4096 + ii * 64 + j; }
    } else if (i < PK_APB) { src = ab; off = i - PK_AB; }
    else if (i < PK_RB) { src = apb; off = i - PK_APB; }
    else if (i < PK_ABIN) { src = rb; off = i - PK_RB; }
    else if (i < PK_AVEC) { src = abin; off = i - PK_ABIN; }
    else { src = avec; off = i - PK_AVEC; }
    wbuf[i] = f32w ? ((const float*)src)[off] : b2f(((const bf16*)src)[off]);
    return;
  }
  int g = (bid - PACK_BLOCKS) * 256 + tid;
  if (g < R_NUM) counts[g] = 0;
  if (bid == PACK_BLOCKS && tid < 64) stb[E_NUM + tid] = 0;
}

// ---------------- transform core: 4 fused streams, LDS-STAGED weights (chunked) -------------
// R10 post-mortem: xform grid fully co-resident -> wall = per-wave latency chain; the ~48
// serialized L2 weight loads/wave were the chain. Now: 4 waves cooperatively stage 16KB
// weight chunks into LDS (coalesced, latency amortized), hot loop reads LDS only.
// FMA order/values identical to R8/R10 -> bit-identical output.

static __device__ __forceinline__ void xf4s(const float (*sW)[64], float* __restrict__ sWt,
                                            int tid, int l, const float* __restrict__ wbuf,
                                            int r0, unsigned int* __restrict__ XMp,
                                            float2* __restrict__ HR) {
  int j = tid & 63;
  float axt[8] = {};
  float amt[8] = {};
  float axh[8] = {};
  float ars[8] = {};
  for (int c = 0; c < 4; c++) {
    __syncthreads();  // prior sWt readers done
    {
      const float4* src = (const float4*)(wbuf + PK_XF + l * 16384 + c * 4096);
      float4* dst = (float4*)sWt;
      for (int k = tid; k < 1024; k += 256) dst[k] = src[k];
    }
    __syncthreads();  // chunk staged
#pragma unroll
    for (int gg = 0; gg < 4; gg++) {
      int g = c * 4 + gg;
      const float* Wg = sWt + gg * 1024 + j * 4;
      float4 w0 = *(const float4*)&Wg[0];    // pwb
      float4 w1 = *(const float4*)&Wg[256];  // aw
      float4 w2 = *(const float4*)&Wg[512];  // pwt
      float4 w3 = *(const float4*)&Wg[768];  // rw
      float4 ev[8];
#pragma unroll
      for (int n = 0; n < 8; n++) ev[n] = *(const float4*)&sW[n][g * 4];
#pragma unroll
      for (int di = 0; di < 4; di++) {
        float wt = ((const float*)&w0)[di];
        float wm = ((const float*)&w1)[di];
        float wh = ((const float*)&w2)[di];
        float wr = ((const float*)&w3)[di];
#pragma unroll
        for (int n = 0; n < 8; n++) {
          float e = ((const float*)&ev[n])[di];
          axt[n] = fmaf(e, wt, axt[n]);
          amt[n] = fmaf(e, wm, amt[n]);
          axh[n] = fmaf(e, wh, axh[n]);
          ars[n] = fmaf(e, wr, ars[n]);
        }
      }
    }
  }
  float abj = wbuf[PK_AB + l * 64 + j];
  float pbj = wbuf[PK_APB + l * 64 + j];
  float rbj = wbuf[PK_RB + l * 64 + j];
#pragma unroll
  for (int n = 0; n < 8; n++) {
    XMp[(size_t)(r0 + n) * 64 + j] = packxm(axt[n], amt[n] + abj);
    HR[(size_t)(r0 + n) * 64 + j] = make_float2(axh[n] + pbj, fmaxf(ars[n] + rbj, 0.f));
  }
}

// ---------------- kA: 32-row 4-wave xform blocks (staged weights) + hist blocks ------------

template <typename T>
static __device__ __forceinline__ void kA_xform(const T* __restrict__ A,
                                                const float* __restrict__ wbuf, int r0,
                                                unsigned int* __restrict__ XMp0,
                                                float2* __restrict__ HR0, float (*sW)[64],
                                                float* __restrict__ sWt, int tid) {
  int j = tid & 63;
  for (int k = j; k < 512; k += 64) {
    sW[k >> 6][k & 63] = ldv(A, (size_t)(r0 + (k >> 6)) * 64 + (k & 63));
  }
  // stage all of P1 (16KB) cooperatively
  {
    const float4* src = (const float4*)(wbuf + PK_P1);
    float4* dst = (float4*)sWt;
    for (int k = tid; k < 1024; k += 256) dst[k] = src[k];
  }
  __syncthreads();
  float a[8] = {0.f, 0.f, 0.f, 0.f, 0.f, 0.f, 0.f, 0.f};
  for (int g = 0; g < 16; g++) {
    float4 wv4 = *(const float4*)&sWt[g * 256 + j * 4];
    float4 ev[8];
#pragma unroll
    for (int n = 0; n < 8; n++) ev[n] = *(const float4*)&sW[n][g * 4];
#pragma unroll
    for (int di = 0; di < 4; di++) {
      float wv = ((const float*)&wv4)[di];
#pragma unroll
      for (int n = 0; n < 8; n++) a[n] = fmaf(((const float*)&ev[n])[di], wv, a[n]);
    }
  }
  float bj = wbuf[PK_P1B + j];
#pragma unroll
  for (int n = 0; n < 8; n++) {
    a[n] = fmaxf(a[n] + bj, 0.f);
    sW[n][j] = a[n];  // wave-private slice: no barrier needed before same-wave reads
  }
  xf4s((const float(*)[64])sW, sWt, tid, 0, wbuf, r0, XMp0, HR0);
}

__global__ void __launch_bounds__(256, 4) kA(const unsigned int* __restrict__ trip_w,
                                             const int* __restrict__ flag,
                                             const void* __restrict__ A,
                                             const float* __restrict__ wbuf,
                                             int* __restrict__ counts, int* __restrict__ rank,
                                             unsigned int* __restrict__ XMp0,
                                             float2* __restrict__ HR0) {
  if (blockIdx.x >= XF_BLOCKS) {
    int e = (blockIdx.x - XF_BLOCKS) * 256 + threadIdx.x;
    if (e < E_NUM) {
      int h = flag[0] ? (int)trip_w[6 * e] : (int)trip_w[3 * e];
      rank[e] = atomicAdd(&counts[h], 1);
    }
    return;
  }
  __shared__ float sA[32][64];   // 8KB: 4 wave-private 8-row slices
  __shared__ float sWt[4096];    // 16KB: cooperative weight staging
  int tid = threadIdx.x;
  int w = tid >> 6;
  int r0 = blockIdx.x * 32 + w * 8;
  float(*sW)[64] = (float(*)[64]) & sA[w * 8][0];
  if (flag[1])
    kA_xform<float>((const float*)A, wbuf, r0, XMp0, HR0, sW, sWt, tid);
  else
    kA_xform<bf16>((const bf16*)A, wbuf, r0, XMp0, HR0, sW, sWt, tid);
}

// ---------------- single-block scan: counts -> exclusive row_ptr[0..R] (1 launch) ----------

__global__ void __launch_bounds__(1024) k_scan1(const int* __restrict__ counts,
                                                int* __restrict__ row_ptr) {
  __shared__ int sp[1024];
  int tid = threadIdx.x;
  int base = tid * 40;  // 1000 threads x 40 = 40000
  int local[40];
  int s = 0;
  if (base < R_NUM) {
#pragma unroll
    for (int k = 0; k < 40; k++) {
      int v = counts[base + k];
      local[k] = s;
      s += v;
    }
  }
  sp[tid] = s;
  __syncthreads();
  for (int off = 1; off < 1024; off <<= 1) {
    int t = (tid >= off) ? sp[tid - off] : 0;
    __syncthreads();
    sp[tid] += t;
    __syncthreads();
  }
  int pre = (tid == 0) ? 0 : sp[tid - 1];
  if (base < R_NUM) {
#pragma unroll
    for (int k = 0; k < 40; k++) row_ptr[base + k] = pre + local[k];
  }
  if (tid == 1023) row_ptr[R_NUM] = sp[1023];  // = E_NUM
}

// atomic-free scatter: pos = row base + precomputed rank (row_ptr stays exclusive)
__global__ void k_scatter2(const unsigned int* __restrict__ trip_w, const int* __restrict__ flag,
                           const int* __restrict__ row_ptr, const int* __restrict__ rank,
                           int* __restrict__ stb) {
  int e = blockIdx.x * 256 + threadIdx.x;
  if (e >= E_NUM) return;
  int h, t, b;
  load_edge(trip_w, e, flag[0], h, t, b);
  int pos = row_ptr[h] + rank[e];
  stb[pos] = (t & 0xFFFF) | (b << 16);
}

// ---------------- pure edge aggregation body (1 row/wave, window-16, tail-clamped) ---------
// row_ptr exclusive: beg = rp[r], end = rp[r+1].

static __device__ __forceinline__ void edge_body(int l, const int* __restrict__ row_ptr,
                                                 const int* __restrict__ stb,
                                                 const unsigned int* __restrict__ XMp,
                                                 const float2* __restrict__ HR,
                                                 const float* __restrict__ wbuf,
                                                 float* __restrict__ out, float* sab) {
  int tid = threadIdx.x;
  int lane = tid & 63;
  int w = tid >> 6;
  int hh = lane >> 3;
  if (tid < 80) {
    float a = wbuf[PK_ABIN + l * 80 + tid];
    sab[tid] = (a > 0.f) ? a : 0.2f * a;
  }
  __syncthreads();
  float av = wbuf[PK_AVEC + l * 64 + lane];

  int r = blockIdx.x * 4 + w;
  float2 hr = HR[(size_t)r * 64 + lane];
  int beg = row_ptr[r];
  int end = row_ptr[r + 1];
  beg = __builtin_amdgcn_readfirstlane(beg);
  end = __builtin_amdgcn_readfirstlane(end);

  float xh = hr.x;
  float num = 0.f, den = 0.f;
  int t0 = (beg < end) ? (stb[beg] & 0xFFFF) : 0;  // clamp target for padded gathers
  for (int jj = beg; jj < end; jj += 16) {
    int pk[16];
    unsigned int xp[16];
#pragma unroll
    for (int k = 0; k < 16; k++) pk[k] = stb[jj + k];  // uniform scalar loads
#pragma unroll
    for (int k = 0; k < 16; k++) {
      int t = (jj + k < end) ? (pk[k] & 0xFFFF) : t0;  // wave-uniform select
      xp[k] = XMp[(size_t)t * 64 + lane];              // 16 gathers in flight
    }
#pragma unroll
    for (int k = 0; k < 16; k++) {
      float xt = __uint_as_float(xp[k] << 16);
      float mt = __uint_as_float(xp[k] & 0xFFFF0000u);
      float z = xh + xt;
      z = (z > 0.f) ? z : 0.2f * z;
      float v = z * av;
      v += __shfl_xor(v, 1);
      v += __shfl_xor(v, 2);
      v += __shfl_xor(v, 4);
      float e = __expf(v + sab[(pk[k] >> 16) * 8 + hh]);
      e = (jj + k < end) ? e : 0.f;
      den += e;
      num = fmaf(mt, e, num);
    }
  }
  out[(size_t)r * 64 + lane] = fmaxf(num / (den + 1e-16f), 0.f) + hr.y;
}

// kE0: edge layer 0 -> emb (d_out used as scratch)
__global__ void __launch_bounds__(256, 8) kE0(const int* __restrict__ row_ptr,
                                              const int* __restrict__ stb,
                                              const unsigned int* __restrict__ XMp0,
                                              const float2* __restrict__ HR0,
                                              const float* __restrict__ wbuf,
                                              float* __restrict__ emb) {
  __shared__ float sab[80];
  edge_body(0, row_ptr, stb, XMp0, HR0, wbuf, emb, sab);
}

// kC: edge layer 1 -> final output
__global__ void __launch_bounds__(256, 8) kC(const int* __restrict__ row_ptr,
                                             const int* __restrict__ stb,
                                             const unsigned int* __restrict__ XMp1,
                                             const float2* __restrict__ HR1,
                                             const float* __restrict__ wbuf,
                                             float* __restrict__ out) {
  __shared__ float sab[80];
  edge_body(1, row_ptr, stb, XMp1, HR1, wbuf, out, sab);
}

// ---------------- kX1: layer-1 32-row 4-wave transform (staged weights) --------------------

__global__ void __launch_bounds__(256, 4) kX1(const float* __restrict__ emb,
                                              const float* __restrict__ wbuf,
                                              unsigned int* __restrict__ XMp1,
                                              float2* __restrict__ HR1) {
  __shared__ float sE[32][64];
  __shared__ float sWt[4096];
  int tid = threadIdx.x;
  int j = tid & 63;
  int w = tid >> 6;
  int r0 = blockIdx.x * 32 + w * 8;
  float(*sW)[64] = (float(*)[64]) & sE[w * 8][0];
  for (int k = j; k < 512; k += 64) {
    sW[k >> 6][k & 63] = emb[(size_t)(r0 + (k >> 6)) * 64 + (k & 63)];
  }
  // wave-private slice; xf4s's first barrier orders the staging buffer
  xf4s((const float(*)[64])sW, sWt, tid, 1, wbuf, r0, XMp1, HR1);
}

// ==================== legacy fallback (tiny ws): wconv + PlanD ====================

__global__ void k_detect_init(const unsigned int* __restrict__ trip_w,
                              const unsigned short* __restrict__ emb_w, int* __restrict__ flag,
                              int* __restrict__ counts, int* __restrict__ stb) {
  int tid = threadIdx.x;
  if (blockIdx.x == 0) {
    if (tid < 64) {
      int lane = tid;
      unsigned int acc = 0;
      for (int i = lane; i < 1024; i += 64) acc |= trip_w[2 * i + 1];
      int votes = 0;
      for (int i = lane; i < 2048; i += 64) {
        unsigned short u = emb_w[2 * i];
        int ex = (u >> 7) & 0xFF;
        if (ex >= 90 && ex <= 130) votes++;
      }
      for (int off = 1; off < 64; off <<= 1) {
        acc |= __shfl_xor(acc, off);
        votes += __shfl_xor(votes, off);
      }
      if (lane == 0) {
        flag[0] = (acc == 0) ? 1 : 0;
        flag[1] = (votes < 1024) ? 1 : 0;
      }
    }
    return;
  }
  int g = (blockIdx.x - 1) * 256 + tid;
  for (int i = g; i < R_NUM; i += 159 * 256) counts[i] = 0;
  if (blockIdx.x == 1 && tid < 64) stb[E_NUM + tid] = 0;
}

__global__ void k_hist_wconv(const unsigned int* __restrict__ trip_w, const int* __restrict__ flag,
                             int* __restrict__ counts, const void* p1w, const void* p1b,
                             const void* apw, const void* apb, const void* abin, const void* avec,
                             const void* aw, const void* ab, const void* rw, const void* rb,
                             float* __restrict__ wbuf) {
  if (blockIdx.x < WCONV_BLOCKS) {
    int i = blockIdx.x * 256 + threadIdx.x;
    if (i >= W_END) return;
    const void* src;
    int off;
    if (i < W_P1B) { src = p1w; off = i - W_P1W; }
    else if (i < W_APW) { src = p1b; off = i - W_P1B; }
    else if (i < W_APB) { src = apw; off = i - W_APW; }
    else if (i < W_ABIN) { src = apb; off = i - W_APB; }
    else if (i < W_AVEC) { src = abin; off = i - W_ABIN; }
    else if (i < W_AW) { src = avec; off = i - W_AVEC; }
    else if (i < W_AB) { src = aw; off = i - W_AW; }
    else if (i < W_RW) { src = ab; off = i - W_AB; }
    else if (i < W_RB) { src = rw; off = i - W_RW; }
    else { src = rb; off = i - W_RB; }
    wbuf[i] = flag[1] ? ((const float*)src)[off] : b2f(((const bf16*)src)[off]);
    return;
  }
  int e = (blockIdx.x - WCONV_BLOCKS) * 256 + threadIdx.x;
  if (e >= E_NUM) return;
  int h, t, b;
  load_edge(trip_w, e, flag[0], h, t, b);
  atomicAdd(&counts[h], 1);
}

// legacy scatter (bumps row_ptr; k_edge_d reads rp[r-1]/rp[r])
__global__ void k_scatter(const unsigned int* __restrict__ trip_w, const int* __restrict__ flag,
                          int* __restrict__ row_ptr, int* __restrict__ stb) {
  int e = blockIdx.x * 256 + threadIdx.x;
  if (e >= E_NUM) return;
  int h, t, b;
  load_edge(trip_w, e, flag[0], h, t, b);
  int pos = atomicAdd(&row_ptr[h], 1);
  stb[pos] = (t & 0xFFFF) | (b << 16);
}

__global__ void k_emb0(const void* __restrict__ A, const int* __restrict__ flag,
                       const float* __restrict__ wbuf, float* __restrict__ emb) {
  int j = threadIdx.x & 63;
  int g = threadIdx.x >> 6;
  int r0 = blockIdx.x * 16 + g * 4;
  int f32 = flag[1];
  __shared__ float sA[16][64];
  for (int k = threadIdx.x; k < 1024; k += 256) {
    int rr = k >> 6, cc = k & 63;
    size_t idx = (size_t)(blockIdx.x * 16 + rr) * 64 + cc;
    sA[rr][cc] = f32 ? ((const float*)A)[idx] : b2f(((const bf16*)A)[idx]);
  }
  __syncthreads();
  const float* W = wbuf + W_P1W;
  float a[4] = {0.f, 0.f, 0.f, 0.f};
  int base = g * 4;
  for (int i = 0; i < 64; i++) {
    float w = W[i * 64 + j];
#pragma unroll
    for (int n = 0; n < 4; n++) a[n] = fmaf(sA[base + n][i], w, a[n]);
  }
  float bj = wbuf[W_P1B + j];
#pragma unroll
  for (int n = 0; n < 4; n++)
    emb[(size_t)(r0 + n) * 64 + j] = fmaxf(a[n] + bj, 0.f);
}

static __device__ __forceinline__ float dotcol(const float* __restrict__ Wm, float val, int lane) {
  float acc = 0.f;
  for (int i = 0; i < 64; i++) acc = fmaf(__shfl(val, i), Wm[i * 64 + lane], acc);
  return acc;
}

template <typename TIN, typename TOUT>
__global__ void k_edge_d(const int* __restrict__ row_ptr, const int* __restrict__ stb,
                         const float* __restrict__ wbuf, int l, const TIN* __restrict__ emb_in,
                         TOUT* __restrict__ emb_out) {
  __shared__ float sab[80];
  int tid = threadIdx.x;
  int lane = tid & 63;
  int w = tid >> 6;
  int r = blockIdx.x * 4 + w;
  int hh = lane >> 3;
  if (tid < 80) {
    float a = wbuf[W_ABIN + l * 80 + tid];
    sab[tid] = (a > 0.f) ? a : 0.2f * a;
  }
  __syncthreads();
  const float* pwt = wbuf + W_APW + l * 8192;
  const float* pwb = pwt + 4096;
  const float* aw = wbuf + W_AW + l * 4096;
  const float* rw = wbuf + W_RW + l * 4096;

  float ev = ldv(emb_in, (size_t)r * 64 + lane);
  float xh = wbuf[W_APB + l * 64 + lane];
  float res = wbuf[W_RB + l * 64 + lane];
  for (int i = 0; i < 64; i++) {
    float e = __shfl(ev, i);
    xh = fmaf(e, pwt[i * 64 + lane], xh);
    res = fmaf(e, rw[i * 64 + lane], res);
  }
  res = fmaxf(res, 0.f);
  float av = wbuf[W_AVEC + l * 64 + lane];
  float abl = wbuf[W_AB + l * 64 + lane];

  int beg = (r == 0) ? 0 : row_ptr[r - 1];
  int end = row_ptr[r];
  float num = 0.f, den = 0.f;
  for (int j = beg; j < end; j++) {
    int p = stb[j];
    int t = p & 0xFFFF;
    float tv = ldv(emb_in, (size_t)t * 64 + lane);
    float z = xh + dotcol(pwb, tv, lane);
    z = (z > 0.f) ? z : 0.2f * z;
    float v = z * av;
    v += __shfl_xor(v, 1);
    v += __shfl_xor(v, 2);
    v += __shfl_xor(v, 4);
    float e = __expf(v + sab[(p >> 16) * 8 + hh]);
    den += e;
    float mt = dotcol(aw, tv, lane) + abl;
    num = fmaf(mt, e, num);
  }
  stv(emb_out, (size_t)r * 64 + lane, fmaxf(num / (den + 1e-16f), 0.f) + res);
}

// ---------------- launch ----------------

extern "C" void kernel_launch(void* const* d_in, const int* in_sizes, int n_in,
                              void* d_out, int out_size, void* d_ws, size_t ws_size,
                              hipStream_t stream) {
  const unsigned int* trip_w = (const unsigned int*)d_in[0];
  const void* rel_emb = d_in[1];
  float* emb = (float*)d_out;
  char* ws = (char*)d_ws;

  if (ws_size >= NEED2) {
    int* counts = (int*)(ws + N_CNTS);
    int* row_ptr = (int*)(ws + N_ROWP);
    int* rank = (int*)(ws + N_RANK);
    int* stb = (int*)(ws + N_STB);
    int* flag = (int*)(ws + N_FLAG);
    float* wbuf = (float*)(ws + N_WBUF);
    unsigned int* XMp0 = (unsigned int*)(ws + N_XMP0);
    float2* HR0 = (float2*)(ws + N_HR0);
    unsigned int* XMp1 = (unsigned int*)(ws + N_XMP1);
    float2* HR1 = (float2*)(ws + N_HR1);

    k_init<<<INIT_BLOCKS, 256, 0, stream>>>(trip_w, (const unsigned short*)rel_emb, flag, counts,
                                            stb, d_in[2], d_in[3], d_in[4], d_in[5], d_in[6],
                                            d_in[7], d_in[8], d_in[9], d_in[10], d_in[11], wbuf);
    kA<<<XF_BLOCKS + HIST_BLOCKS, 256, 0, stream>>>(trip_w, flag, rel_emb, wbuf, counts, rank,
                                                    XMp0, HR0);
    k_scan1<<<1, 1024, 0, stream>>>(counts, row_ptr);
    k_scatter2<<<HIST_BLOCKS, 256, 0, stream>>>(trip_w, flag, row_ptr, rank, stb);
    kE0<<<R_NUM / 4, 256, 0, stream>>>(row_ptr, stb, XMp0, HR0, wbuf, emb);
    kX1<<<XF_BLOCKS, 256, 0, stream>>>(emb, wbuf, XMp1, HR1);
    kC<<<R_NUM / 4, 256, 0, stream>>>(row_ptr, stb, XMp1, HR1, wbuf, emb);
    return;
  }

  // ---- tiny-ws fallback: legacy wconv + PlanD per-edge recompute ----
  {
    int* flag = (int*)(ws + O_FLAG);
    float* wbuf = (float*)(ws + O_WBUF);
    int* row_ptr = (int*)(ws + O_ROWP);
    int* counts = (int*)(ws + O_CNTS);
    int* stb = (int*)(ws + O_STB);
    char* big = ws + O_BIG;

    k_detect_init<<<160, 256, 0, stream>>>(trip_w, (const unsigned short*)rel_emb, flag, counts,
                                           stb);
    k_hist_wconv<<<WCONV_BLOCKS + HIST_BLOCKS, 256, 0, stream>>>(
        trip_w, flag, counts, d_in[2], d_in[3], d_in[4], d_in[5], d_in[6], d_in[7], d_in[8],
        d_in[9], d_in[10], d_in[11], wbuf);
    // legacy inclusive scan via single block (writes exclusive then scatter bumps)
    k_scan1<<<1, 1024, 0, stream>>>(counts, row_ptr);
    k_scatter<<<HIST_BLOCKS, 256, 0, stream>>>(trip_w, flag, row_ptr, stb);
    k_emb0<<<R_NUM / 16, 256, 0, stream>>>(rel_emb, flag, wbuf, emb);
    bf16* embB = (bf16*)big;
    k_edge_d<float, bf16><<<R_NUM / 4, 256, 0, stream>>>(row_ptr, stb, wbuf, 0, emb, embB);
    k_edge_d<bf16, float><<<R_NUM / 4, 256, 0, stream>>>(row_ptr, stb, wbuf, 1, embB, emb);
  }
}

// Round 12
// 234.796 us; speedup vs baseline: 1.1500x; 1.1500x over previous
//
#include <hip/hip_runtime.h>
#include <hip/hip_bf16.h>

typedef __hip_bfloat16 bf16;

#define R_NUM 40000
#define E_NUM 500000
#define HIST_BLOCKS 1954   // ceil(E/256)
#define XF_BLOCKS 1250     // R/32: 32-row blocks = 4 waves x 8 rows, wave-private
#define ZERO_BLOCKS 157    // ceil(R/256)

// ---- packed wbuf layout (f32 element offsets) ----
// PK_P1 : p1w packed [g][j][di]           (16*256)
// PK_XF : [l][g][m][j][di], m=0:pwb 1:aw 2:pwt 3:rw   (2*16*4*256)
#define PK_P1 0
#define PK_P1B 4096
#define PK_XF 4160
#define PK_AB 36928
#define PK_APB 37056
#define PK_RB 37184
#define PK_ABIN 37312
#define PK_AVEC 37472
#define PK_END 37600
#define PACK_BLOCKS 147  // ceil(PK_END/256)
#define INIT_BLOCKS (PACK_BLOCKS + ZERO_BLOCKS)

// ---------------- new-path ws layout (bytes) ----------------
#define N_CNTS 0          // 160000
#define N_ROWP 160000     // 40001 ints (incl. row_ptr[R]=E), padded
#define N_RANK 320256     // E ints
#define N_STB 2320384     // E*4 + 256 zero pad -> ends 4,320,640
#define N_FLAG 4320640    // 2 ints
#define N_WBUF 4320896    // PK_END*4 = 150400 -> ends 4,471,296
#define N_XMP0 4471296
#define N_HR0 14711296
#define N_XMP1 35191296
#define N_HR1 45431296
#define NEED2 65911296ull

// ---------------- legacy (PlanD fallback) ws layout ----------------
#define W_P1W 0
#define W_P1B 4096
#define W_APW 4160
#define W_APB 20544
#define W_ABIN 20672
#define W_AVEC 20832
#define W_AW 20960
#define W_AB 29152
#define W_RW 29280
#define W_RB 37472
#define W_END 37600
#define WCONV_BLOCKS 147

#define O_FLAG 0
#define O_WBUF 256
#define O_ROWP 150784
#define O_CNTS 310784
#define O_STB 635136
#define O_BIG 2635392

static __device__ __forceinline__ float b2f(bf16 x) { return __bfloat162float(x); }
static __device__ __forceinline__ float ldv(const float* p, size_t i) { return p[i]; }
static __device__ __forceinline__ float ldv(const bf16* p, size_t i) { return __bfloat162float(p[i]); }
static __device__ __forceinline__ void stv(float* p, size_t i, float v) { p[i] = v; }
static __device__ __forceinline__ void stv(bf16* p, size_t i, float v) { p[i] = __float2bfloat16(v); }

// round-to-nearest-even f32 -> bf16 bits
static __device__ __forceinline__ unsigned int f2bb(float x) {
  union { float f; unsigned int u; } v;
  v.f = x;
  unsigned int r = v.u + 0x7FFFu + ((v.u >> 16) & 1u);
  return r >> 16;
}
static __device__ __forceinline__ unsigned int packxm(float xt, float mt) {
  return f2bb(xt) | (f2bb(mt) << 16);
}

static __device__ __forceinline__ void load_edge(const unsigned int* __restrict__ w, int e,
                                                 int i64, int& h, int& t, int& b) {
  if (i64) {
    h = (int)w[6 * e + 0];
    t = (int)w[6 * e + 2];
    b = (int)w[6 * e + 4];
  } else {
    h = (int)w[3 * e + 0];
    t = (int)w[3 * e + 1];
    b = (int)w[3 * e + 2];
  }
}

// ---------------- k_init: detect + pack + zero counts + stb pad (1 launch) -----------------
// Pack blocks SELF-detect the dtype flags (one wave, ~50 loads, trivial) so detect+pack fuse
// without a cross-block dependency. Block 0 publishes flags for downstream kernels.
// (Kept from R11 — the R11 regression was kA's LDS staging, not this fusion.)

__global__ void __launch_bounds__(256) k_init(
    const unsigned int* __restrict__ trip_w, const unsigned short* __restrict__ emb16,
    int* __restrict__ flag, int* __restrict__ counts, int* __restrict__ stb, const void* p1w,
    const void* p1b, const void* apw, const void* apb, const void* abin, const void* avec,
    const void* aw, const void* ab, const void* rw, const void* rb, float* __restrict__ wbuf) {
  int tid = threadIdx.x;
  int bid = blockIdx.x;
  if (bid < PACK_BLOCKS) {
    __shared__ int sfl;
    if (tid < 64) {
      unsigned int acc = 0;
      for (int i = tid; i < 1024; i += 64) acc |= trip_w[2 * i + 1];
      int votes = 0;
      for (int i = tid; i < 2048; i += 64) {
        unsigned short u = emb16[2 * i];
        int ex = (u >> 7) & 0xFF;
        if (ex >= 90 && ex <= 130) votes++;
      }
      for (int off = 1; off < 64; off <<= 1) {
        acc |= __shfl_xor(acc, off);
        votes += __shfl_xor(votes, off);
      }
      if (tid == 0) {
        sfl = (votes < 1024) ? 1 : 0;
        if (bid == 0) {
          flag[0] = (acc == 0) ? 1 : 0;
          flag[1] = sfl;
        }
      }
    }
    __syncthreads();
    int f32w = sfl;
    int i = bid * 256 + tid;
    if (i >= PK_END) return;
    const void* src;
    int off;
    if (i < PK_P1B) {
      int g = i >> 8, r = i & 255, j = r >> 2, di = r & 3;
      src = p1w;
      off = (g * 4 + di) * 64 + j;
    } else if (i < PK_XF) {
      src = p1b;
      off = i - PK_P1B;
    } else if (i < PK_AB) {
      int t = i - PK_XF;
      int l = t >> 14;
      t &= 16383;
      int g = t >> 10;
      t &= 1023;
      int m = t >> 8;
      int r = t & 255, j = r >> 2, di = r & 3;
      int ii = g * 4 + di;
      if (m == 0) { src = apw; off = l * 8192 + 4096 + ii * 64 + j; }
      else if (m == 1) { src = aw; off = l * 4096 + ii * 64 + j; }
      else if (m == 2) { src = apw; off = l * 8192 + ii * 64 + j; }
      else { src = rw; off = l * 4096 + ii * 64 + j; }
    } else if (i < PK_APB) { src = ab; off = i - PK_AB; }
    else if (i < PK_RB) { src = apb; off = i - PK_APB; }
    else if (i < PK_ABIN) { src = rb; off = i - PK_RB; }
    else if (i < PK_AVEC) { src = abin; off = i - PK_ABIN; }
    else { src = avec; off = i - PK_AVEC; }
    wbuf[i] = f32w ? ((const float*)src)[off] : b2f(((const bf16*)src)[off]);
    return;
  }
  int g = (bid - PACK_BLOCKS) * 256 + tid;
  if (g < R_NUM) counts[g] = 0;
  if (bid == PACK_BLOCKS && tid < 64) stb[E_NUM + tid] = 0;
}

// ---------------- transform core: 4 fused streams, packed float4 weight loads ----------------
// R10 version (proven 45.5us, no spill). sW = the calling wave's private 8-row LDS slice.
// LIVE SET ~90 VGPR: must compile under cap 128 (launch_bounds min-waves 4). min-waves 8
// (cap 64) spills ~30MB to scratch and is 2.5x slower (R9; also R3, R6, R11 variants).

static __device__ __forceinline__ void xf4p(const float (*sW)[64], int j, int l,
                                            const float* __restrict__ wbuf, int r0,
                                            unsigned int* __restrict__ XMp,
                                            float2* __restrict__ HR) {
  const float* W = wbuf + PK_XF + l * 16384;
  float axt[8] = {};
  float amt[8] = {};
  float axh[8] = {};
  float ars[8] = {};
  for (int g = 0; g < 16; g++) {
    const float* Wg = W + g * 1024 + j * 4;
    float4 w0 = *(const float4*)&Wg[0];    // pwb
    float4 w1 = *(const float4*)&Wg[256];  // aw
    float4 w2 = *(const float4*)&Wg[512];  // pwt
    float4 w3 = *(const float4*)&Wg[768];  // rw
    float4 ev[8];
#pragma unroll
    for (int n = 0; n < 8; n++) ev[n] = *(const float4*)&sW[n][g * 4];
#pragma unroll
    for (int di = 0; di < 4; di++) {
      float wt = ((const float*)&w0)[di];
      float wm = ((const float*)&w1)[di];
      float wh = ((const float*)&w2)[di];
      float wr = ((const float*)&w3)[di];
#pragma unroll
      for (int n = 0; n < 8; n++) {
        float e = ((const float*)&ev[n])[di];
        axt[n] = fmaf(e, wt, axt[n]);
        amt[n] = fmaf(e, wm, amt[n]);
        axh[n] = fmaf(e, wh, axh[n]);
        ars[n] = fmaf(e, wr, ars[n]);
      }
    }
  }
  float abj = wbuf[PK_AB + l * 64 + j];
  float pbj = wbuf[PK_APB + l * 64 + j];
  float rbj = wbuf[PK_RB + l * 64 + j];
#pragma unroll
  for (int n = 0; n < 8; n++) {
    XMp[(size_t)(r0 + n) * 64 + j] = packxm(axt[n], amt[n] + abj);
    HR[(size_t)(r0 + n) * 64 + j] = make_float2(axh[n] + pbj, fmaxf(ars[n] + rbj, 0.f));
  }
}

// ---------------- kA: 32-row 4-wave xform blocks (wave-private, NO barriers) + hist --------
// hist records per-edge within-row rank (atomicAdd return) for atomic-free scatter.

template <typename T>
static __device__ __forceinline__ void kA_xform(const T* __restrict__ A,
                                                const float* __restrict__ wbuf, int r0,
                                                unsigned int* __restrict__ XMp0,
                                                float2* __restrict__ HR0, float (*sW)[64]) {
  int j = threadIdx.x & 63;
  for (int k = j; k < 512; k += 64) {
    int rr = k >> 6, cc = k & 63;
    sW[rr][cc] = ldv(A, (size_t)(r0 + rr) * 64 + cc);
  }
  // wave-private slice: no barrier needed
  float a[8] = {0.f, 0.f, 0.f, 0.f, 0.f, 0.f, 0.f, 0.f};
  const float* P1 = wbuf + PK_P1;
  for (int g = 0; g < 16; g++) {
    float4 wv4 = *(const float4*)&P1[g * 256 + j * 4];
    float4 ev[8];
#pragma unroll
    for (int n = 0; n < 8; n++) ev[n] = *(const float4*)&sW[n][g * 4];
#pragma unroll
    for (int di = 0; di < 4; di++) {
      float wv = ((const float*)&wv4)[di];
#pragma unroll
      for (int n = 0; n < 8; n++) a[n] = fmaf(((const float*)&ev[n])[di], wv, a[n]);
    }
  }
  float bj = wbuf[PK_P1B + j];
#pragma unroll
  for (int n = 0; n < 8; n++) {
    a[n] = fmaxf(a[n] + bj, 0.f);
    sW[n][j] = a[n];
  }
  xf4p((const float(*)[64])sW, j, 0, wbuf, r0, XMp0, HR0);
}

__global__ void __launch_bounds__(256, 4) kA(const unsigned int* __restrict__ trip_w,
                                             const int* __restrict__ flag,
                                             const void* __restrict__ A,
                                             const float* __restrict__ wbuf,
                                             int* __restrict__ counts, int* __restrict__ rank,
                                             unsigned int* __restrict__ XMp0,
                                             float2* __restrict__ HR0) {
  if (blockIdx.x >= XF_BLOCKS) {
    int e = (blockIdx.x - XF_BLOCKS) * 256 + threadIdx.x;
    if (e < E_NUM) {
      int h = flag[0] ? (int)trip_w[6 * e] : (int)trip_w[3 * e];
      rank[e] = atomicAdd(&counts[h], 1);
    }
    return;
  }
  __shared__ float sA[32][64];
  int w = threadIdx.x >> 6;
  int r0 = blockIdx.x * 32 + w * 8;
  float(*sW)[64] = (float(*)[64]) & sA[w * 8][0];
  if (flag[1])
    kA_xform<float>((const float*)A, wbuf, r0, XMp0, HR0, sW);
  else
    kA_xform<bf16>((const bf16*)A, wbuf, r0, XMp0, HR0, sW);
}

// ---------------- single-block scan: counts -> exclusive row_ptr[0..R] (1 launch) ----------

__global__ void __launch_bounds__(1024) k_scan1(const int* __restrict__ counts,
                                                int* __restrict__ row_ptr) {
  __shared__ int sp[1024];
  int tid = threadIdx.x;
  int base = tid * 40;  // 1000 threads x 40 = 40000
  int local[40];
  int s = 0;
  if (base < R_NUM) {
#pragma unroll
    for (int k = 0; k < 40; k++) {
      int v = counts[base + k];
      local[k] = s;
      s += v;
    }
  }
  sp[tid] = s;
  __syncthreads();
  for (int off = 1; off < 1024; off <<= 1) {
    int t = (tid >= off) ? sp[tid - off] : 0;
    __syncthreads();
    sp[tid] += t;
    __syncthreads();
  }
  int pre = (tid == 0) ? 0 : sp[tid - 1];
  if (base < R_NUM) {
#pragma unroll
    for (int k = 0; k < 40; k++) row_ptr[base + k] = pre + local[k];
  }
  if (tid == 1023) row_ptr[R_NUM] = sp[1023];  // = E_NUM
}

// atomic-free scatter: pos = row base + precomputed rank (row_ptr stays exclusive)
__global__ void k_scatter2(const unsigned int* __restrict__ trip_w, const int* __restrict__ flag,
                           const int* __restrict__ row_ptr, const int* __restrict__ rank,
                           int* __restrict__ stb) {
  int e = blockIdx.x * 256 + threadIdx.x;
  if (e >= E_NUM) return;
  int h, t, b;
  load_edge(trip_w, e, flag[0], h, t, b);
  int pos = row_ptr[h] + rank[e];
  stb[pos] = (t & 0xFFFF) | (b << 16);
}

// ---------------- pure edge aggregation body (1 row/wave, window-16, tail-clamped) ---------
// row_ptr exclusive: beg = rp[r], end = rp[r+1].

static __device__ __forceinline__ void edge_body(int l, const int* __restrict__ row_ptr,
                                                 const int* __restrict__ stb,
                                                 const unsigned int* __restrict__ XMp,
                                                 const float2* __restrict__ HR,
                                                 const float* __restrict__ wbuf,
                                                 float* __restrict__ out, float* sab) {
  int tid = threadIdx.x;
  int lane = tid & 63;
  int w = tid >> 6;
  int hh = lane >> 3;
  if (tid < 80) {
    float a = wbuf[PK_ABIN + l * 80 + tid];
    sab[tid] = (a > 0.f) ? a : 0.2f * a;
  }
  __syncthreads();
  float av = wbuf[PK_AVEC + l * 64 + lane];

  int r = blockIdx.x * 4 + w;
  float2 hr = HR[(size_t)r * 64 + lane];
  int beg = row_ptr[r];
  int end = row_ptr[r + 1];
  beg = __builtin_amdgcn_readfirstlane(beg);
  end = __builtin_amdgcn_readfirstlane(end);

  float xh = hr.x;
  float num = 0.f, den = 0.f;
  int t0 = (beg < end) ? (stb[beg] & 0xFFFF) : 0;  // clamp target for padded gathers
  for (int jj = beg; jj < end; jj += 16) {
    int pk[16];
    unsigned int xp[16];
#pragma unroll
    for (int k = 0; k < 16; k++) pk[k] = stb[jj + k];  // uniform scalar loads
#pragma unroll
    for (int k = 0; k < 16; k++) {
      int t = (jj + k < end) ? (pk[k] & 0xFFFF) : t0;  // wave-uniform select
      xp[k] = XMp[(size_t)t * 64 + lane];              // 16 gathers in flight
    }
#pragma unroll
    for (int k = 0; k < 16; k++) {
      float xt = __uint_as_float(xp[k] << 16);
      float mt = __uint_as_float(xp[k] & 0xFFFF0000u);
      float z = xh + xt;
      z = (z > 0.f) ? z : 0.2f * z;
      float v = z * av;
      v += __shfl_xor(v, 1);
      v += __shfl_xor(v, 2);
      v += __shfl_xor(v, 4);
      float e = __expf(v + sab[(pk[k] >> 16) * 8 + hh]);
      e = (jj + k < end) ? e : 0.f;
      den += e;
      num = fmaf(mt, e, num);
    }
  }
  out[(size_t)r * 64 + lane] = fmaxf(num / (den + 1e-16f), 0.f) + hr.y;
}

// kE0: edge layer 0 -> emb (d_out used as scratch)
__global__ void __launch_bounds__(256, 8) kE0(const int* __restrict__ row_ptr,
                                              const int* __restrict__ stb,
                                              const unsigned int* __restrict__ XMp0,
                                              const float2* __restrict__ HR0,
                                              const float* __restrict__ wbuf,
                                              float* __restrict__ emb) {
  __shared__ float sab[80];
  edge_body(0, row_ptr, stb, XMp0, HR0, wbuf, emb, sab);
}

// kC: edge layer 1 -> final output
__global__ void __launch_bounds__(256, 8) kC(const int* __restrict__ row_ptr,
                                             const int* __restrict__ stb,
                                             const unsigned int* __restrict__ XMp1,
                                             const float2* __restrict__ HR1,
                                             const float* __restrict__ wbuf,
                                             float* __restrict__ out) {
  __shared__ float sab[80];
  edge_body(1, row_ptr, stb, XMp1, HR1, wbuf, out, sab);
}

// ---------------- kX1: layer-1 32-row 4-wave transform (wave-private): emb -> XMp1/HR1 -----

__global__ void __launch_bounds__(256, 4) kX1(const float* __restrict__ emb,
                                              const float* __restrict__ wbuf,
                                              unsigned int* __restrict__ XMp1,
                                              float2* __restrict__ HR1) {
  __shared__ float sE[32][64];
  int j = threadIdx.x & 63;
  int w = threadIdx.x >> 6;
  int r0 = blockIdx.x * 32 + w * 8;
  float(*sW)[64] = (float(*)[64]) & sE[w * 8][0];
  for (int k = j; k < 512; k += 64) {
    int rr = k >> 6, cc = k & 63;
    sW[rr][cc] = emb[(size_t)(r0 + rr) * 64 + cc];
  }
  // wave-private slice: no barrier needed
  xf4p((const float(*)[64])sW, j, 1, wbuf, r0, XMp1, HR1);
}

// ==================== legacy fallback (tiny ws): wconv + PlanD ====================

__global__ void k_detect_init(const unsigned int* __restrict__ trip_w,
                              const unsigned short* __restrict__ emb_w, int* __restrict__ flag,
                              int* __restrict__ counts, int* __restrict__ stb) {
  int tid = threadIdx.x;
  if (blockIdx.x == 0) {
    if (tid < 64) {
      int lane = tid;
      unsigned int acc = 0;
      for (int i = lane; i < 1024; i += 64) acc |= trip_w[2 * i + 1];
      int votes = 0;
      for (int i = lane; i < 2048; i += 64) {
        unsigned short u = emb_w[2 * i];
        int ex = (u >> 7) & 0xFF;
        if (ex >= 90 && ex <= 130) votes++;
      }
      for (int off = 1; off < 64; off <<= 1) {
        acc |= __shfl_xor(acc, off);
        votes += __shfl_xor(votes, off);
      }
      if (lane == 0) {
        flag[0] = (acc == 0) ? 1 : 0;
        flag[1] = (votes < 1024) ? 1 : 0;
      }
    }
    return;
  }
  int g = (blockIdx.x - 1) * 256 + tid;
  for (int i = g; i < R_NUM; i += 159 * 256) counts[i] = 0;
  if (blockIdx.x == 1 && tid < 64) stb[E_NUM + tid] = 0;
}

__global__ void k_hist_wconv(const unsigned int* __restrict__ trip_w, const int* __restrict__ flag,
                             int* __restrict__ counts, const void* p1w, const void* p1b,
                             const void* apw, const void* apb, const void* abin, const void* avec,
                             const void* aw, const void* ab, const void* rw, const void* rb,
                             float* __restrict__ wbuf) {
  if (blockIdx.x < WCONV_BLOCKS) {
    int i = blockIdx.x * 256 + threadIdx.x;
    if (i >= W_END) return;
    const void* src;
    int off;
    if (i < W_P1B) { src = p1w; off = i - W_P1W; }
    else if (i < W_APW) { src = p1b; off = i - W_P1B; }
    else if (i < W_APB) { src = apw; off = i - W_APW; }
    else if (i < W_ABIN) { src = apb; off = i - W_APB; }
    else if (i < W_AVEC) { src = abin; off = i - W_ABIN; }
    else if (i < W_AW) { src = avec; off = i - W_AVEC; }
    else if (i < W_AB) { src = aw; off = i - W_AW; }
    else if (i < W_RW) { src = ab; off = i - W_AB; }
    else if (i < W_RB) { src = rw; off = i - W_RW; }
    else { src = rb; off = i - W_RB; }
    wbuf[i] = flag[1] ? ((const float*)src)[off] : b2f(((const bf16*)src)[off]);
    return;
  }
  int e = (blockIdx.x - WCONV_BLOCKS) * 256 + threadIdx.x;
  if (e >= E_NUM) return;
  int h, t, b;
  load_edge(trip_w, e, flag[0], h, t, b);
  atomicAdd(&counts[h], 1);
}

// legacy scatter (bumps row_ptr; k_edge_d reads rp[r-1]/rp[r])
__global__ void k_scatter(const unsigned int* __restrict__ trip_w, const int* __restrict__ flag,
                          int* __restrict__ row_ptr, int* __restrict__ stb) {
  int e = blockIdx.x * 256 + threadIdx.x;
  if (e >= E_NUM) return;
  int h, t, b;
  load_edge(trip_w, e, flag[0], h, t, b);
  int pos = atomicAdd(&row_ptr[h], 1);
  stb[pos] = (t & 0xFFFF) | (b << 16);
}

__global__ void k_emb0(const void* __restrict__ A, const int* __restrict__ flag,
                       const float* __restrict__ wbuf, float* __restrict__ emb) {
  int j = threadIdx.x & 63;
  int g = threadIdx.x >> 6;
  int r0 = blockIdx.x * 16 + g * 4;
  int f32 = flag[1];
  __shared__ float sA[16][64];
  for (int k = threadIdx.x; k < 1024; k += 256) {
    int rr = k >> 6, cc = k & 63;
    size_t idx = (size_t)(blockIdx.x * 16 + rr) * 64 + cc;
    sA[rr][cc] = f32 ? ((const float*)A)[idx] : b2f(((const bf16*)A)[idx]);
  }
  __syncthreads();
  const float* W = wbuf + W_P1W;
  float a[4] = {0.f, 0.f, 0.f, 0.f};
  int base = g * 4;
  for (int i = 0; i < 64; i++) {
    float w = W[i * 64 + j];
#pragma unroll
    for (int n = 0; n < 4; n++) a[n] = fmaf(sA[base + n][i], w, a[n]);
  }
  float bj = wbuf[W_P1B + j];
#pragma unroll
  for (int n = 0; n < 4; n++)
    emb[(size_t)(r0 + n) * 64 + j] = fmaxf(a[n] + bj, 0.f);
}

static __device__ __forceinline__ float dotcol(const float* __restrict__ Wm, float val, int lane) {
  float acc = 0.f;
  for (int i = 0; i < 64; i++) acc = fmaf(__shfl(val, i), Wm[i * 64 + lane], acc);
  return acc;
}

template <typename TIN, typename TOUT>
__global__ void k_edge_d(const int* __restrict__ row_ptr, const int* __restrict__ stb,
                         const float* __restrict__ wbuf, int l, const TIN* __restrict__ emb_in,
                         TOUT* __restrict__ emb_out) {
  __shared__ float sab[80];
  int tid = threadIdx.x;
  int lane = tid & 63;
  int w = tid >> 6;
  int r = blockIdx.x * 4 + w;
  int hh = lane >> 3;
  if (tid < 80) {
    float a = wbuf[W_ABIN + l * 80 + tid];
    sab[tid] = (a > 0.f) ? a : 0.2f * a;
  }
  __syncthreads();
  const float* pwt = wbuf + W_APW + l * 8192;
  const float* pwb = pwt + 4096;
  const float* aw = wbuf + W_AW + l * 4096;
  const float* rw = wbuf + W_RW + l * 4096;

  float ev = ldv(emb_in, (size_t)r * 64 + lane);
  float xh = wbuf[W_APB + l * 64 + lane];
  float res = wbuf[W_RB + l * 64 + lane];
  for (int i = 0; i < 64; i++) {
    float e = __shfl(ev, i);
    xh = fmaf(e, pwt[i * 64 + lane], xh);
    res = fmaf(e, rw[i * 64 + lane], res);
  }
  res = fmaxf(res, 0.f);
  float av = wbuf[W_AVEC + l * 64 + lane];
  float abl = wbuf[W_AB + l * 64 + lane];

  int beg = (r == 0) ? 0 : row_ptr[r - 1];
  int end = row_ptr[r];
  float num = 0.f, den = 0.f;
  for (int j = beg; j < end; j++) {
    int p = stb[j];
    int t = p & 0xFFFF;
    float tv = ldv(emb_in, (size_t)t * 64 + lane);
    float z = xh + dotcol(pwb, tv, lane);
    z = (z > 0.f) ? z : 0.2f * z;
    float v = z * av;
    v += __shfl_xor(v, 1);
    v += __shfl_xor(v, 2);
    v += __shfl_xor(v, 4);
    float e = __expf(v + sab[(p >> 16) * 8 + hh]);
    den += e;
    float mt = dotcol(aw, tv, lane) + abl;
    num = fmaf(mt, e, num);
  }
  stv(emb_out, (size_t)r * 64 + lane, fmaxf(num / (den + 1e-16f), 0.f) + res);
}

// ---------------- launch ----------------

extern "C" void kernel_launch(void* const* d_in, const int* in_sizes, int n_in,
                              void* d_out, int out_size, void* d_ws, size_t ws_size,
                              hipStream_t stream) {
  const unsigned int* trip_w = (const unsigned int*)d_in[0];
  const void* rel_emb = d_in[1];
  float* emb = (float*)d_out;
  char* ws = (char*)d_ws;

  if (ws_size >= NEED2) {
    int* counts = (int*)(ws + N_CNTS);
    int* row_ptr = (int*)(ws + N_ROWP);
    int* rank = (int*)(ws + N_RANK);
    int* stb = (int*)(ws + N_STB);
    int* flag = (int*)(ws + N_FLAG);
    float* wbuf = (float*)(ws + N_WBUF);
    unsigned int* XMp0 = (unsigned int*)(ws + N_XMP0);
    float2* HR0 = (float2*)(ws + N_HR0);
    unsigned int* XMp1 = (unsigned int*)(ws + N_XMP1);
    float2* HR1 = (float2*)(ws + N_HR1);

    k_init<<<INIT_BLOCKS, 256, 0, stream>>>(trip_w, (const unsigned short*)rel_emb, flag, counts,
                                            stb, d_in[2], d_in[3], d_in[4], d_in[5], d_in[6],
                                            d_in[7], d_in[8], d_in[9], d_in[10], d_in[11], wbuf);
    kA<<<XF_BLOCKS + HIST_BLOCKS, 256, 0, stream>>>(trip_w, flag, rel_emb, wbuf, counts, rank,
                                                    XMp0, HR0);
    k_scan1<<<1, 1024, 0, stream>>>(counts, row_ptr);
    k_scatter2<<<HIST_BLOCKS, 256, 0, stream>>>(trip_w, flag, row_ptr, rank, stb);
    kE0<<<R_NUM / 4, 256, 0, stream>>>(row_ptr, stb, XMp0, HR0, wbuf, emb);
    kX1<<<XF_BLOCKS, 256, 0, stream>>>(emb, wbuf, XMp1, HR1);
    kC<<<R_NUM / 4, 256, 0, stream>>>(row_ptr, stb, XMp1, HR1, wbuf, emb);
    return;
  }

  // ---- tiny-ws fallback: legacy wconv + PlanD per-edge recompute ----
  {
    int* flag = (int*)(ws + O_FLAG);
    float* wbuf = (float*)(ws + O_WBUF);
    int* row_ptr = (int*)(ws + O_ROWP);
    int* counts = (int*)(ws + O_CNTS);
    int* stb = (int*)(ws + O_STB);
    char* big = ws + O_BIG;

    k_detect_init<<<160, 256, 0, stream>>>(trip_w, (const unsigned short*)rel_emb, flag, counts,
                                           stb);
    k_hist_wconv<<<WCONV_BLOCKS + HIST_BLOCKS, 256, 0, stream>>>(
        trip_w, flag, counts, d_in[2], d_in[3], d_in[4], d_in[5], d_in[6], d_in[7], d_in[8],
        d_in[9], d_in[10], d_in[11], wbuf);
    k_scan1<<<1, 1024, 0, stream>>>(counts, row_ptr);
    k_scatter<<<HIST_BLOCKS, 256, 0, stream>>>(trip_w, flag, row_ptr, stb);
    k_emb0<<<R_NUM / 16, 256, 0, stream>>>(rel_emb, flag, wbuf, emb);
    bf16* embB = (bf16*)big;
    k_edge_d<float, bf16><<<R_NUM / 4, 256, 0, stream>>>(row_ptr, stb, wbuf, 0, emb, embB);
    k_edge_d<bf16, float><<<R_NUM / 4, 256, 0, stream>>>(row_ptr, stb, wbuf, 1, embB, emb);
  }
}

// Round 13
// 229.990 us; speedup vs baseline: 1.1741x; 1.0209x over previous
//
#include <hip/hip_runtime.h>
#include <hip/hip_bf16.h>

typedef __hip_bfloat16 bf16;

#define R_NUM 40000
#define E_NUM 500000
#define HIST_BLOCKS 1954   // ceil(E/256) (scatter grid)
#define XF_BLOCKS 2500     // R/16: 16-row blocks = 2 waves x 8 rows, wave-private
#define HB128 3907         // ceil(E/128) hist blocks at 128 threads
#define ZERO_BLOCKS 157    // ceil(R/256)

// ---- packed wbuf layout (f32 element offsets) ----
// PK_P1 : p1w packed [g][j][di]           (16*256)
// PK_XF : [l][g][m][j][di], m=0:pwb 1:aw 2:pwt 3:rw   (2*16*4*256)
#define PK_P1 0
#define PK_P1B 4096
#define PK_XF 4160
#define PK_AB 36928
#define PK_APB 37056
#define PK_RB 37184
#define PK_ABIN 37312
#define PK_AVEC 37472
#define PK_END 37600
#define PACK_BLOCKS 147  // ceil(PK_END/256)
#define INIT_BLOCKS (PACK_BLOCKS + ZERO_BLOCKS)

// ---------------- new-path ws layout (bytes) ----------------
#define N_CNTS 0          // 160000
#define N_ROWP 160000     // 40001 ints (incl. row_ptr[R]=E), padded
#define N_RANK 320256     // E ints
#define N_STB 2320384     // E*4 + 256 zero pad -> ends 4,320,640
#define N_FLAG 4320640    // 2 ints
#define N_WBUF 4320896    // PK_END*4 = 150400 -> ends 4,471,296
#define N_XMP0 4471296
#define N_HR0 14711296
#define N_XMP1 35191296
#define N_HR1 45431296
#define NEED2 65911296ull

// ---------------- legacy (PlanD fallback) ws layout ----------------
#define W_P1W 0
#define W_P1B 4096
#define W_APW 4160
#define W_APB 20544
#define W_ABIN 20672
#define W_AVEC 20832
#define W_AW 20960
#define W_AB 29152
#define W_RW 29280
#define W_RB 37472
#define W_END 37600
#define WCONV_BLOCKS 147

#define O_FLAG 0
#define O_WBUF 256
#define O_ROWP 150784
#define O_CNTS 310784
#define O_STB 635136
#define O_BIG 2635392

static __device__ __forceinline__ float b2f(bf16 x) { return __bfloat162float(x); }
static __device__ __forceinline__ float ldv(const float* p, size_t i) { return p[i]; }
static __device__ __forceinline__ float ldv(const bf16* p, size_t i) { return __bfloat162float(p[i]); }
static __device__ __forceinline__ void stv(float* p, size_t i, float v) { p[i] = v; }
static __device__ __forceinline__ void stv(bf16* p, size_t i, float v) { p[i] = __float2bfloat16(v); }

// round-to-nearest-even f32 -> bf16 bits
static __device__ __forceinline__ unsigned int f2bb(float x) {
  union { float f; unsigned int u; } v;
  v.f = x;
  unsigned int r = v.u + 0x7FFFu + ((v.u >> 16) & 1u);
  return r >> 16;
}
static __device__ __forceinline__ unsigned int packxm(float xt, float mt) {
  return f2bb(xt) | (f2bb(mt) << 16);
}

static __device__ __forceinline__ void load_edge(const unsigned int* __restrict__ w, int e,
                                                 int i64, int& h, int& t, int& b) {
  if (i64) {
    h = (int)w[6 * e + 0];
    t = (int)w[6 * e + 2];
    b = (int)w[6 * e + 4];
  } else {
    h = (int)w[3 * e + 0];
    t = (int)w[3 * e + 1];
    b = (int)w[3 * e + 2];
  }
}

// ---------------- k_init: detect + pack + zero counts + stb pad (1 launch) -----------------
// Pack blocks SELF-detect the dtype flags (one wave, ~50 loads, trivial) so detect+pack fuse
// without a cross-block dependency. Block 0 publishes flags for downstream kernels.

__global__ void __launch_bounds__(256) k_init(
    const unsigned int* __restrict__ trip_w, const unsigned short* __restrict__ emb16,
    int* __restrict__ flag, int* __restrict__ counts, int* __restrict__ stb, const void* p1w,
    const void* p1b, const void* apw, const void* apb, const void* abin, const void* avec,
    const void* aw, const void* ab, const void* rw, const void* rb, float* __restrict__ wbuf) {
  int tid = threadIdx.x;
  int bid = blockIdx.x;
  if (bid < PACK_BLOCKS) {
    __shared__ int sfl;
    if (tid < 64) {
      unsigned int acc = 0;
      for (int i = tid; i < 1024; i += 64) acc |= trip_w[2 * i + 1];
      int votes = 0;
      for (int i = tid; i < 2048; i += 64) {
        unsigned short u = emb16[2 * i];
        int ex = (u >> 7) & 0xFF;
        if (ex >= 90 && ex <= 130) votes++;
      }
      for (int off = 1; off < 64; off <<= 1) {
        acc |= __shfl_xor(acc, off);
        votes += __shfl_xor(votes, off);
      }
      if (tid == 0) {
        sfl = (votes < 1024) ? 1 : 0;
        if (bid == 0) {
          flag[0] = (acc == 0) ? 1 : 0;
          flag[1] = sfl;
        }
      }
    }
    __syncthreads();
    int f32w = sfl;
    int i = bid * 256 + tid;
    if (i >= PK_END) return;
    const void* src;
    int off;
    if (i < PK_P1B) {
      int g = i >> 8, r = i & 255, j = r >> 2, di = r & 3;
      src = p1w;
      off = (g * 4 + di) * 64 + j;
    } else if (i < PK_XF) {
      src = p1b;
      off = i - PK_P1B;
    } else if (i < PK_AB) {
      int t = i - PK_XF;
      int l = t >> 14;
      t &= 16383;
      int g = t >> 10;
      t &= 1023;
      int m = t >> 8;
      int r = t & 255, j = r >> 2, di = r & 3;
      int ii = g * 4 + di;
      if (m == 0) { src = apw; off = l * 8192 + 4096 + ii * 64 + j; }
      else if (m == 1) { src = aw; off = l * 4096 + ii * 64 + j; }
      else if (m == 2) { src = apw; off = l * 8192 + ii * 64 + j; }
      else { src = rw; off = l * 4096 + ii * 64 + j; }
    } else if (i < PK_APB) { src = ab; off = i - PK_AB; }
    else if (i < PK_RB) { src = apb; off = i - PK_APB; }
    else if (i < PK_ABIN) { src = rb; off = i - PK_RB; }
    else if (i < PK_AVEC) { src = abin; off = i - PK_ABIN; }
    else { src = avec; off = i - PK_AVEC; }
    wbuf[i] = f32w ? ((const float*)src)[off] : b2f(((const bf16*)src)[off]);
    return;
  }
  int g = (bid - PACK_BLOCKS) * 256 + tid;
  if (g < R_NUM) counts[g] = 0;
  if (bid == PACK_BLOCKS && tid < 64) stb[E_NUM + tid] = 0;
}

// ---------------- transform core: 4 fused streams, packed float4 weight loads ----------------
// R10 version (proven no-spill). sW = the calling wave's private 8-row LDS slice.
// LIVE SET ~90 VGPR: must compile under cap 128 (launch_bounds min-waves 4 at 256thr,
// equivalently cap >=128 at 128thr). Tighter caps spill ~30MB scratch, 2.5x slower (R9/R3/R6/R11).

static __device__ __forceinline__ void xf4p(const float (*sW)[64], int j, int l,
                                            const float* __restrict__ wbuf, int r0,
                                            unsigned int* __restrict__ XMp,
                                            float2* __restrict__ HR) {
  const float* W = wbuf + PK_XF + l * 16384;
  float axt[8] = {};
  float amt[8] = {};
  float axh[8] = {};
  float ars[8] = {};
  for (int g = 0; g < 16; g++) {
    const float* Wg = W + g * 1024 + j * 4;
    float4 w0 = *(const float4*)&Wg[0];    // pwb
    float4 w1 = *(const float4*)&Wg[256];  // aw
    float4 w2 = *(const float4*)&Wg[512];  // pwt
    float4 w3 = *(const float4*)&Wg[768];  // rw
    float4 ev[8];
#pragma unroll
    for (int n = 0; n < 8; n++) ev[n] = *(const float4*)&sW[n][g * 4];
#pragma unroll
    for (int di = 0; di < 4; di++) {
      float wt = ((const float*)&w0)[di];
      float wm = ((const float*)&w1)[di];
      float wh = ((const float*)&w2)[di];
      float wr = ((const float*)&w3)[di];
#pragma unroll
      for (int n = 0; n < 8; n++) {
        float e = ((const float*)&ev[n])[di];
        axt[n] = fmaf(e, wt, axt[n]);
        amt[n] = fmaf(e, wm, amt[n]);
        axh[n] = fmaf(e, wh, axh[n]);
        ars[n] = fmaf(e, wr, ars[n]);
      }
    }
  }
  float abj = wbuf[PK_AB + l * 64 + j];
  float pbj = wbuf[PK_APB + l * 64 + j];
  float rbj = wbuf[PK_RB + l * 64 + j];
#pragma unroll
  for (int n = 0; n < 8; n++) {
    XMp[(size_t)(r0 + n) * 64 + j] = packxm(axt[n], amt[n] + abj);
    HR[(size_t)(r0 + n) * 64 + j] = make_float2(axh[n] + pbj, fmaxf(ars[n] + rbj, 0.f));
  }
}

// ---------------- kA: 16-row 2-wave xform blocks (wave-private, NO barriers) + hist --------
// R13: 128-thread blocks double the WG-slot wave count (R8: 64-thr blocks capped at ~16 WG/CU;
// 128-thr x 16 WG = 32 waves/CU) AND halve the per-block latency chain — both residency
// models predict a gain. Per-wave codegen identical to R10/R12 (same j/w split, same xf4p).
// hist records per-edge within-row rank (atomicAdd return) for atomic-free scatter.

template <typename T>
static __device__ __forceinline__ void kA_xform(const T* __restrict__ A,
                                                const float* __restrict__ wbuf, int r0,
                                                unsigned int* __restrict__ XMp0,
                                                float2* __restrict__ HR0, float (*sW)[64]) {
  int j = threadIdx.x & 63;
  for (int k = j; k < 512; k += 64) {
    int rr = k >> 6, cc = k & 63;
    sW[rr][cc] = ldv(A, (size_t)(r0 + rr) * 64 + cc);
  }
  // wave-private slice: no barrier needed
  float a[8] = {0.f, 0.f, 0.f, 0.f, 0.f, 0.f, 0.f, 0.f};
  const float* P1 = wbuf + PK_P1;
  for (int g = 0; g < 16; g++) {
    float4 wv4 = *(const float4*)&P1[g * 256 + j * 4];
    float4 ev[8];
#pragma unroll
    for (int n = 0; n < 8; n++) ev[n] = *(const float4*)&sW[n][g * 4];
#pragma unroll
    for (int di = 0; di < 4; di++) {
      float wv = ((const float*)&wv4)[di];
#pragma unroll
      for (int n = 0; n < 8; n++) a[n] = fmaf(((const float*)&ev[n])[di], wv, a[n]);
    }
  }
  float bj = wbuf[PK_P1B + j];
#pragma unroll
  for (int n = 0; n < 8; n++) {
    a[n] = fmaxf(a[n] + bj, 0.f);
    sW[n][j] = a[n];
  }
  xf4p((const float(*)[64])sW, j, 0, wbuf, r0, XMp0, HR0);
}

__global__ void __launch_bounds__(128, 4) kA(const unsigned int* __restrict__ trip_w,
                                             const int* __restrict__ flag,
                                             const void* __restrict__ A,
                                             const float* __restrict__ wbuf,
                                             int* __restrict__ counts, int* __restrict__ rank,
                                             unsigned int* __restrict__ XMp0,
                                             float2* __restrict__ HR0) {
  if (blockIdx.x >= XF_BLOCKS) {
    int e = (blockIdx.x - XF_BLOCKS) * 128 + threadIdx.x;
    if (e < E_NUM) {
      int h = flag[0] ? (int)trip_w[6 * e] : (int)trip_w[3 * e];
      rank[e] = atomicAdd(&counts[h], 1);
    }
    return;
  }
  __shared__ float sA[16][64];  // 4KB: 2 wave-private 8-row slices
  int w = threadIdx.x >> 6;
  int r0 = blockIdx.x * 16 + w * 8;
  float(*sW)[64] = (float(*)[64]) & sA[w * 8][0];
  if (flag[1])
    kA_xform<float>((const float*)A, wbuf, r0, XMp0, HR0, sW);
  else
    kA_xform<bf16>((const bf16*)A, wbuf, r0, XMp0, HR0, sW);
}

// ---------------- single-block scan: counts -> exclusive row_ptr[0..R] (1 launch) ----------

__global__ void __launch_bounds__(1024) k_scan1(const int* __restrict__ counts,
                                                int* __restrict__ row_ptr) {
  __shared__ int sp[1024];
  int tid = threadIdx.x;
  int base = tid * 40;  // 1000 threads x 40 = 40000
  int local[40];
  int s = 0;
  if (base < R_NUM) {
#pragma unroll
    for (int k = 0; k < 40; k++) {
      int v = counts[base + k];
      local[k] = s;
      s += v;
    }
  }
  sp[tid] = s;
  __syncthreads();
  for (int off = 1; off < 1024; off <<= 1) {
    int t = (tid >= off) ? sp[tid - off] : 0;
    __syncthreads();
    sp[tid] += t;
    __syncthreads();
  }
  int pre = (tid == 0) ? 0 : sp[tid - 1];
  if (base < R_NUM) {
#pragma unroll
    for (int k = 0; k < 40; k++) row_ptr[base + k] = pre + local[k];
  }
  if (tid == 1023) row_ptr[R_NUM] = sp[1023];  // = E_NUM
}

// atomic-free scatter: pos = row base + precomputed rank (row_ptr stays exclusive)
__global__ void k_scatter2(const unsigned int* __restrict__ trip_w, const int* __restrict__ flag,
                           const int* __restrict__ row_ptr, const int* __restrict__ rank,
                           int* __restrict__ stb) {
  int e = blockIdx.x * 256 + threadIdx.x;
  if (e >= E_NUM) return;
  int h, t, b;
  load_edge(trip_w, e, flag[0], h, t, b);
  int pos = row_ptr[h] + rank[e];
  stb[pos] = (t & 0xFFFF) | (b << 16);
}

// ---------------- pure edge aggregation body (1 row/wave, window-16, tail-clamped) ---------
// row_ptr exclusive: beg = rp[r], end = rp[r+1].

static __device__ __forceinline__ void edge_body(int l, const int* __restrict__ row_ptr,
                                                 const int* __restrict__ stb,
                                                 const unsigned int* __restrict__ XMp,
                                                 const float2* __restrict__ HR,
                                                 const float* __restrict__ wbuf,
                                                 float* __restrict__ out, float* sab) {
  int tid = threadIdx.x;
  int lane = tid & 63;
  int w = tid >> 6;
  int hh = lane >> 3;
  if (tid < 80) {
    float a = wbuf[PK_ABIN + l * 80 + tid];
    sab[tid] = (a > 0.f) ? a : 0.2f * a;
  }
  __syncthreads();
  float av = wbuf[PK_AVEC + l * 64 + lane];

  int r = blockIdx.x * 4 + w;
  float2 hr = HR[(size_t)r * 64 + lane];
  int beg = row_ptr[r];
  int end = row_ptr[r + 1];
  beg = __builtin_amdgcn_readfirstlane(beg);
  end = __builtin_amdgcn_readfirstlane(end);

  float xh = hr.x;
  float num = 0.f, den = 0.f;
  int t0 = (beg < end) ? (stb[beg] & 0xFFFF) : 0;  // clamp target for padded gathers
  for (int jj = beg; jj < end; jj += 16) {
    int pk[16];
    unsigned int xp[16];
#pragma unroll
    for (int k = 0; k < 16; k++) pk[k] = stb[jj + k];  // uniform scalar loads
#pragma unroll
    for (int k = 0; k < 16; k++) {
      int t = (jj + k < end) ? (pk[k] & 0xFFFF) : t0;  // wave-uniform select
      xp[k] = XMp[(size_t)t * 64 + lane];              // 16 gathers in flight
    }
#pragma unroll
    for (int k = 0; k < 16; k++) {
      float xt = __uint_as_float(xp[k] << 16);
      float mt = __uint_as_float(xp[k] & 0xFFFF0000u);
      float z = xh + xt;
      z = (z > 0.f) ? z : 0.2f * z;
      float v = z * av;
      v += __shfl_xor(v, 1);
      v += __shfl_xor(v, 2);
      v += __shfl_xor(v, 4);
      float e = __expf(v + sab[(pk[k] >> 16) * 8 + hh]);
      e = (jj + k < end) ? e : 0.f;
      den += e;
      num = fmaf(mt, e, num);
    }
  }
  out[(size_t)r * 64 + lane] = fmaxf(num / (den + 1e-16f), 0.f) + hr.y;
}

// kE0: edge layer 0 -> emb (d_out used as scratch)
__global__ void __launch_bounds__(256, 8) kE0(const int* __restrict__ row_ptr,
                                              const int* __restrict__ stb,
                                              const unsigned int* __restrict__ XMp0,
                                              const float2* __restrict__ HR0,
                                              const float* __restrict__ wbuf,
                                              float* __restrict__ emb) {
  __shared__ float sab[80];
  edge_body(0, row_ptr, stb, XMp0, HR0, wbuf, emb, sab);
}

// kC: edge layer 1 -> final output
__global__ void __launch_bounds__(256, 8) kC(const int* __restrict__ row_ptr,
                                             const int* __restrict__ stb,
                                             const unsigned int* __restrict__ XMp1,
                                             const float2* __restrict__ HR1,
                                             const float* __restrict__ wbuf,
                                             float* __restrict__ out) {
  __shared__ float sab[80];
  edge_body(1, row_ptr, stb, XMp1, HR1, wbuf, out, sab);
}

// ---------------- kX1: layer-1 16-row 2-wave transform (wave-private): emb -> XMp1/HR1 -----

__global__ void __launch_bounds__(128, 4) kX1(const float* __restrict__ emb,
                                              const float* __restrict__ wbuf,
                                              unsigned int* __restrict__ XMp1,
                                              float2* __restrict__ HR1) {
  __shared__ float sE[16][64];
  int j = threadIdx.x & 63;
  int w = threadIdx.x >> 6;
  int r0 = blockIdx.x * 16 + w * 8;
  float(*sW)[64] = (float(*)[64]) & sE[w * 8][0];
  for (int k = j; k < 512; k += 64) {
    int rr = k >> 6, cc = k & 63;
    sW[rr][cc] = emb[(size_t)(r0 + rr) * 64 + cc];
  }
  // wave-private slice: no barrier needed
  xf4p((const float(*)[64])sW, j, 1, wbuf, r0, XMp1, HR1);
}

// ==================== legacy fallback (tiny ws): wconv + PlanD ====================

__global__ void k_detect_init(const unsigned int* __restrict__ trip_w,
                              const unsigned short* __restrict__ emb_w, int* __restrict__ flag,
                              int* __restrict__ counts, int* __restrict__ stb) {
  int tid = threadIdx.x;
  if (blockIdx.x == 0) {
    if (tid < 64) {
      int lane = tid;
      unsigned int acc = 0;
      for (int i = lane; i < 1024; i += 64) acc |= trip_w[2 * i + 1];
      int votes = 0;
      for (int i = lane; i < 2048; i += 64) {
        unsigned short u = emb_w[2 * i];
        int ex = (u >> 7) & 0xFF;
        if (ex >= 90 && ex <= 130) votes++;
      }
      for (int off = 1; off < 64; off <<= 1) {
        acc |= __shfl_xor(acc, off);
        votes += __shfl_xor(votes, off);
      }
      if (lane == 0) {
        flag[0] = (acc == 0) ? 1 : 0;
        flag[1] = (votes < 1024) ? 1 : 0;
      }
    }
    return;
  }
  int g = (blockIdx.x - 1) * 256 + tid;
  for (int i = g; i < R_NUM; i += 159 * 256) counts[i] = 0;
  if (blockIdx.x == 1 && tid < 64) stb[E_NUM + tid] = 0;
}

__global__ void k_hist_wconv(const unsigned int* __restrict__ trip_w, const int* __restrict__ flag,
                             int* __restrict__ counts, const void* p1w, const void* p1b,
                             const void* apw, const void* apb, const void* abin, const void* avec,
                             const void* aw, const void* ab, const void* rw, const void* rb,
                             float* __restrict__ wbuf) {
  if (blockIdx.x < WCONV_BLOCKS) {
    int i = blockIdx.x * 256 + threadIdx.x;
    if (i >= W_END) return;
    const void* src;
    int off;
    if (i < W_P1B) { src = p1w; off = i - W_P1W; }
    else if (i < W_APW) { src = p1b; off = i - W_P1B; }
    else if (i < W_APB) { src = apw; off = i - W_APW; }
    else if (i < W_ABIN) { src = apb; off = i - W_APB; }
    else if (i < W_AVEC) { src = abin; off = i - W_ABIN; }
    else if (i < W_AW) { src = avec; off = i - W_AVEC; }
    else if (i < W_AB) { src = aw; off = i - W_AW; }
    else if (i < W_RW) { src = ab; off = i - W_AB; }
    else if (i < W_RB) { src = rw; off = i - W_RW; }
    else { src = rb; off = i - W_RB; }
    wbuf[i] = flag[1] ? ((const float*)src)[off] : b2f(((const bf16*)src)[off]);
    return;
  }
  int e = (blockIdx.x - WCONV_BLOCKS) * 256 + threadIdx.x;
  if (e >= E_NUM) return;
  int h, t, b;
  load_edge(trip_w, e, flag[0], h, t, b);
  atomicAdd(&counts[h], 1);
}

// legacy scatter (bumps row_ptr; k_edge_d reads rp[r-1]/rp[r])
__global__ void k_scatter(const unsigned int* __restrict__ trip_w, const int* __restrict__ flag,
                          int* __restrict__ row_ptr, int* __restrict__ stb) {
  int e = blockIdx.x * 256 + threadIdx.x;
  if (e >= E_NUM) return;
  int h, t, b;
  load_edge(trip_w, e, flag[0], h, t, b);
  int pos = atomicAdd(&row_ptr[h], 1);
  stb[pos] = (t & 0xFFFF) | (b << 16);
}

__global__ void k_emb0(const void* __restrict__ A, const int* __restrict__ flag,
                       const float* __restrict__ wbuf, float* __restrict__ emb) {
  int j = threadIdx.x & 63;
  int g = threadIdx.x >> 6;
  int r0 = blockIdx.x * 16 + g * 4;
  int f32 = flag[1];
  __shared__ float sA[16][64];
  for (int k = threadIdx.x; k < 1024; k += 256) {
    int rr = k >> 6, cc = k & 63;
    size_t idx = (size_t)(blockIdx.x * 16 + rr) * 64 + cc;
    sA[rr][cc] = f32 ? ((const float*)A)[idx] : b2f(((const bf16*)A)[idx]);
  }
  __syncthreads();
  const float* W = wbuf + W_P1W;
  float a[4] = {0.f, 0.f, 0.f, 0.f};
  int base = g * 4;
  for (int i = 0; i < 64; i++) {
    float w = W[i * 64 + j];
#pragma unroll
    for (int n = 0; n < 4; n++) a[n] = fmaf(sA[base + n][i], w, a[n]);
  }
  float bj = wbuf[W_P1B + j];
#pragma unroll
  for (int n = 0; n < 4; n++)
    emb[(size_t)(r0 + n) * 64 + j] = fmaxf(a[n] + bj, 0.f);
}

static __device__ __forceinline__ float dotcol(const float* __restrict__ Wm, float val, int lane) {
  float acc = 0.f;
  for (int i = 0; i < 64; i++) acc = fmaf(__shfl(val, i), Wm[i * 64 + lane], acc);
  return acc;
}

template <typename TIN, typename TOUT>
__global__ void k_edge_d(const int* __restrict__ row_ptr, const int* __restrict__ stb,
                         const float* __restrict__ wbuf, int l, const TIN* __restrict__ emb_in,
                         TOUT* __restrict__ emb_out) {
  __shared__ float sab[80];
  int tid = threadIdx.x;
  int lane = tid & 63;
  int w = tid >> 6;
  int r = blockIdx.x * 4 + w;
  int hh = lane >> 3;
  if (tid < 80) {
    float a = wbuf[W_ABIN + l * 80 + tid];
    sab[tid] = (a > 0.f) ? a : 0.2f * a;
  }
  __syncthreads();
  const float* pwt = wbuf + W_APW + l * 8192;
  const float* pwb = pwt + 4096;
  const float* aw = wbuf + W_AW + l * 4096;
  const float* rw = wbuf + W_RW + l * 4096;

  float ev = ldv(emb_in, (size_t)r * 64 + lane);
  float xh = wbuf[W_APB + l * 64 + lane];
  float res = wbuf[W_RB + l * 64 + lane];
  for (int i = 0; i < 64; i++) {
    float e = __shfl(ev, i);
    xh = fmaf(e, pwt[i * 64 + lane], xh);
    res = fmaf(e, rw[i * 64 + lane], res);
  }
  res = fmaxf(res, 0.f);
  float av = wbuf[W_AVEC + l * 64 + lane];
  float abl = wbuf[W_AB + l * 64 + lane];

  int beg = (r == 0) ? 0 : row_ptr[r - 1];
  int end = row_ptr[r];
  float num = 0.f, den = 0.f;
  for (int j = beg; j < end; j++) {
    int p = stb[j];
    int t = p & 0xFFFF;
    float tv = ldv(emb_in, (size_t)t * 64 + lane);
    float z = xh + dotcol(pwb, tv, lane);
    z = (z > 0.f) ? z : 0.2f * z;
    float v = z * av;
    v += __shfl_xor(v, 1);
    v += __shfl_xor(v, 2);
    v += __shfl_xor(v, 4);
    float e = __expf(v + sab[(p >> 16) * 8 + hh]);
    den += e;
    float mt = dotcol(aw, tv, lane) + abl;
    num = fmaf(mt, e, num);
  }
  stv(emb_out, (size_t)r * 64 + lane, fmaxf(num / (den + 1e-16f), 0.f) + res);
}

// ---------------- launch ----------------

extern "C" void kernel_launch(void* const* d_in, const int* in_sizes, int n_in,
                              void* d_out, int out_size, void* d_ws, size_t ws_size,
                              hipStream_t stream) {
  const unsigned int* trip_w = (const unsigned int*)d_in[0];
  const void* rel_emb = d_in[1];
  float* emb = (float*)d_out;
  char* ws = (char*)d_ws;

  if (ws_size >= NEED2) {
    int* counts = (int*)(ws + N_CNTS);
    int* row_ptr = (int*)(ws + N_ROWP);
    int* rank = (int*)(ws + N_RANK);
    int* stb = (int*)(ws + N_STB);
    int* flag = (int*)(ws + N_FLAG);
    float* wbuf = (float*)(ws + N_WBUF);
    unsigned int* XMp0 = (unsigned int*)(ws + N_XMP0);
    float2* HR0 = (float2*)(ws + N_HR0);
    unsigned int* XMp1 = (unsigned int*)(ws + N_XMP1);
    float2* HR1 = (float2*)(ws + N_HR1);

    k_init<<<INIT_BLOCKS, 256, 0, stream>>>(trip_w, (const unsigned short*)rel_emb, flag, counts,
                                            stb, d_in[2], d_in[3], d_in[4], d_in[5], d_in[6],
                                            d_in[7], d_in[8], d_in[9], d_in[10], d_in[11], wbuf);
    kA<<<XF_BLOCKS + HB128, 128, 0, stream>>>(trip_w, flag, rel_emb, wbuf, counts, rank, XMp0,
                                              HR0);
    k_scan1<<<1, 1024, 0, stream>>>(counts, row_ptr);
    k_scatter2<<<HIST_BLOCKS, 256, 0, stream>>>(trip_w, flag, row_ptr, rank, stb);
    kE0<<<R_NUM / 4, 256, 0, stream>>>(row_ptr, stb, XMp0, HR0, wbuf, emb);
    kX1<<<XF_BLOCKS, 128, 0, stream>>>(emb, wbuf, XMp1, HR1);
    kC<<<R_NUM / 4, 256, 0, stream>>>(row_ptr, stb, XMp1, HR1, wbuf, emb);
    return;
  }

  // ---- tiny-ws fallback: legacy wconv + PlanD per-edge recompute ----
  {
    int* flag = (int*)(ws + O_FLAG);
    float* wbuf = (float*)(ws + O_WBUF);
    int* row_ptr = (int*)(ws + O_ROWP);
    int* counts = (int*)(ws + O_CNTS);
    int* stb = (int*)(ws + O_STB);
    char* big = ws + O_BIG;

    k_detect_init<<<160, 256, 0, stream>>>(trip_w, (const unsigned short*)rel_emb, flag, counts,
                                           stb);
    k_hist_wconv<<<WCONV_BLOCKS + HIST_BLOCKS, 256, 0, stream>>>(
        trip_w, flag, counts, d_in[2], d_in[3], d_in[4], d_in[5], d_in[6], d_in[7], d_in[8],
        d_in[9], d_in[10], d_in[11], wbuf);
    k_scan1<<<1, 1024, 0, stream>>>(counts, row_ptr);
    k_scatter<<<HIST_BLOCKS, 256, 0, stream>>>(trip_w, flag, row_ptr, stb);
    k_emb0<<<R_NUM / 16, 256, 0, stream>>>(rel_emb, flag, wbuf, emb);
    bf16* embB = (bf16*)big;
    k_edge_d<float, bf16><<<R_NUM / 4, 256, 0, stream>>>(row_ptr, stb, wbuf, 0, emb, embB);
    k_edge_d<bf16, float><<<R_NUM / 4, 256, 0, stream>>>(row_ptr, stb, wbuf, 1, embB, emb);
  }
}